// Round 1
// baseline (86.616 us; speedup 1.0000x reference)
//
#include <hip/hip_runtime.h>

// Problem: B=16, S=2048, D=64, fp32.
// out[b] = V[b] @ (K[b]^T @ Q[b])   -- avoids the SxS intermediate.
//
// R6: occupancy fix. Grid is 256 blocks (= CU count) in both kernels, so each
// CU holds ONE block; at 256/512 threads that was 1-2 waves/SIMD -> ds_read
// latency (~120cyc) exposed. Now 1024-thread blocks:
//   A: 4 s-groups x 256 thr, each accumulates partial M over 32 of the 128
//      staged rows (same 4x4 tiles), LDS-reduce tail. 16 waves/CU (was 4).
//   B: 2 dp-groups x 512 thr over 32 of 64 dp each, LDS-reduce tail.
//      16 waves/CU (was 8).
// Same global traffic, same P layout, same math order per 4x4 tile.

typedef float vf4 __attribute__((ext_vector_type(4)));

#define BATCH 16
#define SEQ   2048
#define DIM   64
#define SCHUNK 128                 // seq rows per block, kernel A
#define NCHUNK (SEQ / SCHUNK)      // 16
#define ROWS2  128                 // V rows per block, kernel B
#define TPADR  132                 // transposed-V row stride (floats), 16B-aligned
#define RPAD   68                  // reduce-scratch row stride (floats), 272B: b128-aligned, bank-spread

// ---------------- Kernel A: P[bx] = K_chunk^T @ Q_chunk ----------------------
// 1024 threads = 4 s-groups x 256. Group g covers s = g*32 .. g*32+31.
// Thread (ty,tx) in each group owns M[ty*4..+3][tx*4..+3] partial.
__global__ __launch_bounds__(1024, 1) void ktq_part_kernel(
        const float* __restrict__ K, const float* __restrict__ Q,
        float* __restrict__ P) {
    __shared__ __attribute__((aligned(16))) float Smem[2 * SCHUNK * DIM];  // 64 KB
    float* Ks = Smem;                  // 32 KB
    float* Qs = Smem + SCHUNK * DIM;   // 32 KB
    const int b     = blockIdx.y;
    const int chunk = blockIdx.x;
    const int t     = threadIdx.x;

    const float* Kb = K + ((size_t)b * SEQ + (size_t)chunk * SCHUNK) * DIM;
    const float* Qb = Q + ((size_t)b * SEQ + (size_t)chunk * SCHUNK) * DIM;

    // Stage: 2048 vf4 each; 1024 threads -> 2 each, coalesced.
#pragma unroll
    for (int i = 0; i < 2; ++i) {
        int idx = i * 1024 + t;
        ((vf4*)Ks)[idx] = ((const vf4*)Kb)[idx];
        ((vf4*)Qs)[idx] = ((const vf4*)Qb)[idx];
    }
    __syncthreads();

    const int g   = t >> 8;    // s-group 0..3
    const int sub = t & 255;
    const int tx  = sub & 15;  // d  (Q) cols tx*4 .. +3
    const int ty  = sub >> 4;  // d' (K) rows ty*4 .. +3
    float acc[4][4] = {};

    const float* KsG = Ks + (g * 32) * DIM;
    const float* QsG = Qs + (g * 32) * DIM;
#pragma unroll 4
    for (int s = 0; s < 32; ++s) {
        vf4 ak = *(const vf4*)&KsG[s * DIM + ty * 4];  // 4 distinct/wave, broadcast
        vf4 bq = *(const vf4*)&QsG[s * DIM + tx * 4];  // 16 distinct, 2-way (free)
#pragma unroll
        for (int i = 0; i < 4; ++i)
#pragma unroll
            for (int j = 0; j < 4; ++j) acc[i][j] += ak[i] * bq[j];
    }

    // Cross-group reduce: groups 1..3 park partials in (reused) staging LDS,
    // group 0 sums and stores. 3*64*RPAD floats = 52 KB <= 64 KB.
    __syncthreads();               // everyone done reading Ks/Qs
    float* Rs = Smem;
    if (g != 0) {
#pragma unroll
        for (int i = 0; i < 4; ++i) {
            vf4 r = {acc[i][0], acc[i][1], acc[i][2], acc[i][3]};
            *(vf4*)&Rs[((g - 1) * 64 + ty * 4 + i) * RPAD + tx * 4] = r;
        }
    }
    __syncthreads();
    if (g == 0) {
        float* Pb = P + ((size_t)b * NCHUNK + chunk) * DIM * DIM;
#pragma unroll
        for (int i = 0; i < 4; ++i) {
            vf4 sum = {acc[i][0], acc[i][1], acc[i][2], acc[i][3]};
#pragma unroll
            for (int g2 = 0; g2 < 3; ++g2)
                sum += *(const vf4*)&Rs[(g2 * 64 + ty * 4 + i) * RPAD + tx * 4];
            *(vf4*)&Pb[(ty * 4 + i) * DIM + tx * 4] = sum;
        }
    }
}

// ---------------- Kernel B: O rows = V rows @ sum_c P[b][c] ------------------
// 1024 threads = 2 dp-groups x 512. Group g covers dp = g*32 .. g*32+31.
__global__ __launch_bounds__(1024, 1) void vm_red_kernel(
        const float* __restrict__ V, const float* __restrict__ P,
        float* __restrict__ O) {
    __shared__ __attribute__((aligned(16))) float Ml[DIM * DIM];      // 16 KB, M[d'][d]
    __shared__ __attribute__((aligned(16))) float VsT[DIM * TPADR];   // 33 KB, VsT[col][row]
    const int b  = blockIdx.y;
    const int rb = blockIdx.x;
    const int t  = threadIdx.x;

    // Reduce the 16 partials of this batch: 1024 vf4 / 1024 thr -> 1 each.
    const float* Pb = P + (size_t)b * NCHUNK * DIM * DIM;
    {
        vf4 sum = ((const vf4*)Pb)[t];
#pragma unroll
        for (int c = 1; c < NCHUNK; ++c)
            sum += ((const vf4*)(Pb + (size_t)c * DIM * DIM))[t];
        ((vf4*)Ml)[t] = sum;
    }

    // Stage 128 V rows transposed: 2048 vf4 -> 2 each (one-time scatter).
    const float* Vb = V + ((size_t)b * SEQ + (size_t)rb * ROWS2) * DIM;
#pragma unroll
    for (int i = 0; i < 2; ++i) {
        int idx = i * 1024 + t;
        int row = idx >> 4;          // 0..127
        int col = (idx & 15) * 4;    // 0..60
        vf4 v = ((const vf4*)Vb)[idx];
        VsT[(col + 0) * TPADR + row] = v[0];
        VsT[(col + 1) * TPADR + row] = v[1];
        VsT[(col + 2) * TPADR + row] = v[2];
        VsT[(col + 3) * TPADR + row] = v[3];
    }
    __syncthreads();

    const int g   = t >> 9;    // dp-group 0..1
    const int sub = t & 511;
    const int tx  = sub & 15;  // output cols d = tx*4 .. +3
    const int ty  = sub >> 4;  // output rows v = ty*4 .. +3 (0..31 -> 128 rows)
    float acc[4][4] = {};

#pragma unroll 4
    for (int d0 = 0; d0 < 32; ++d0) {
        int dp = g * 32 + d0;
        vf4 mv = *(const vf4*)&Ml[dp * DIM + tx * 4];
        vf4 av = *(const vf4*)&VsT[dp * TPADR + ty * 4];
#pragma unroll
        for (int i = 0; i < 4; ++i)
#pragma unroll
            for (int j = 0; j < 4; ++j) acc[i][j] += av[i] * mv[j];
    }

    // Cross-group reduce: group 1 parks partial in (reused) VsT, group 0 sums.
    __syncthreads();               // everyone done reading VsT
    float* Rs = VsT;               // 8192 floats = 32 KB <= 33 KB
    if (g == 1) {
#pragma unroll
        for (int i = 0; i < 4; ++i) {
            vf4 r = {acc[i][0], acc[i][1], acc[i][2], acc[i][3]};
            *(vf4*)&Rs[(ty * 4 + i) * DIM + tx * 4] = r;
        }
    }
    __syncthreads();
    if (g == 0) {
        float* Ob = O + ((size_t)b * SEQ + (size_t)rb * ROWS2) * DIM;
#pragma unroll
        for (int i = 0; i < 4; ++i) {
            vf4 r = *(const vf4*)&Rs[(ty * 4 + i) * DIM + tx * 4];
            vf4 o = {acc[i][0] + r[0], acc[i][1] + r[1],
                     acc[i][2] + r[2], acc[i][3] + r[3]};
            __builtin_nontemporal_store(o, (vf4*)&Ob[(ty * 4 + i) * DIM + tx * 4]);
        }
    }
}

extern "C" void kernel_launch(void* const* d_in, const int* in_sizes, int n_in,
                              void* d_out, int out_size, void* d_ws, size_t ws_size,
                              hipStream_t stream) {
    const float* Q = (const float*)d_in[0];
    const float* K = (const float*)d_in[1];
    const float* V = (const float*)d_in[2];
    float* O = (float*)d_out;
    float* P = (float*)d_ws;   // BATCH*NCHUNK*64*64 floats = 4 MB of partials

    dim3 gridA(NCHUNK, BATCH);        // 256 blocks, 1024 thr, 16 waves/CU
    ktq_part_kernel<<<gridA, 1024, 0, stream>>>(K, Q, P);

    dim3 gridB(SEQ / ROWS2, BATCH);   // 256 blocks, 1024 thr, 16 waves/CU
    vm_red_kernel<<<gridB, 1024, 0, stream>>>(V, P, O);
}